// Round 4
// baseline (705.074 us; speedup 1.0000x reference)
//
#include <hip/hip_runtime.h>

// ---------------------------------------------------------------------------
// 3-layer GCN: out = ReLU(Â(ReLU(Â(Â (X W1^T) +b1) W2^T +b2)) W3^T) +b3
// Â = D^{-1/2}(A+I)D^{-1/2}, deg = in-degree + 1 (self loop).
// Dtype plan: xs (GEMM out) = bf16 plane [N][C]; h (agg out) = bf16 hi/lo
// planes (split-bf16 ~ f32); GEMM = split-bf16 MFMA (xh*wh + xl*wh + xh*wl).
//
// R15: CHANNEL-partitioned aggregate for C=128 layers. R12-R14 pm: node-
// partitioned gather forces every XCD to pull the whole 25.6MB xs (fetch
// 187MB ~= 8 XCD x footprint floor; three request-scheduling structures all
// 67-69us). Now block handles chgroup cg = blockIdx.x & 7 (16 ch = 32B per
// node); under round-robin block->XCD dispatch each XCD's gather slice is
// N*32B = 3.2MB -> L2-RESIDENT. 2 lanes per node, 4 edges/chunk ascending =
// same add order as v4 => bit-identical result. cols re-read 8x but is
// L3-resident. C=64 final aggregate stays v4 (one variable per round).
// ---------------------------------------------------------------------------

#define NPB 256          // nodes per bucket (bucket = dst >> 8)
#define CAP 4672         // edges capacity per bucket region
#define BIN_WGS 512      // workgroups in bin_edges

typedef short bfrag __attribute__((ext_vector_type(8)));       // 8 bf16
typedef float f32x4 __attribute__((ext_vector_type(4)));
typedef unsigned short u16x8 __attribute__((ext_vector_type(8)));

__global__ __launch_bounds__(256) void bin_edges(const int* __restrict__ src,
                                                 const int* __restrict__ dst,
                                                 int* __restrict__ cur,
                                                 int* __restrict__ binned,
                                                 int E, int B) {
  __shared__ int lc[512];
  __shared__ int lbase[512];
  const int t = threadIdx.x;
  const int chunk = (E + BIN_WGS - 1) / BIN_WGS;
  const int e0 = blockIdx.x * chunk;
  const int e1 = min(E, e0 + chunk);

  for (int i = t; i < B; i += 256) lc[i] = 0;
  __syncthreads();
  for (int e = e0 + t; e < e1; e += 256) {
    int d = dst[e];
    atomicAdd(&lc[d >> 8], 1);
  }
  __syncthreads();
  for (int i = t; i < B; i += 256) {
    int c = lc[i];
    lbase[i] = c ? atomicAdd(&cur[i], c) : 0;
    lc[i] = 0;
  }
  __syncthreads();
  for (int e = e0 + t; e < e1; e += 256) {
    int d = dst[e];
    int s = __builtin_nontemporal_load(&src[e]);
    int bk = d >> 8;
    int p = lbase[bk] + atomicAdd(&lc[bk], 1);
    if (p < (bk + 1) * CAP)
      binned[p] = ((d & 255) << 24) | s;
  }
}

__global__ __launch_bounds__(256) void build_buckets(const int* __restrict__ binned,
                                                     const int* __restrict__ cur,
                                                     int* __restrict__ cols,
                                                     int2* __restrict__ off2,
                                                     float* __restrict__ dinv,
                                                     int N) {
  __shared__ int eb[CAP];
  __shared__ int ob[CAP];
  __shared__ int lc[256];
  __shared__ int sc[256];
  const int b = blockIdx.x;
  const int t = threadIdx.x;
  const int base = b * CAP;
  const int cntb = min(cur[b] - base, CAP);

  for (int i = t; i < cntb; i += 256) eb[i] = binned[base + i];
  lc[t] = 0;
  __syncthreads();
  for (int i = t; i < cntb; i += 256)
    atomicAdd(&lc[(unsigned)eb[i] >> 24], 1);
  __syncthreads();
  int myc = lc[t];
  sc[t] = myc;
  __syncthreads();
  for (int d = 1; d < 256; d <<= 1) {
    int a = (t >= d) ? sc[t - d] : 0;
    __syncthreads();
    sc[t] += a;
    __syncthreads();
  }
  int excl = sc[t] - myc;
  int node = b * NPB + t;
  if (node < N) {
    off2[node] = make_int2(base + excl, base + excl + myc);
    dinv[node] = rsqrtf((float)(myc + 1));
  }
  lc[t] = excl;
  __syncthreads();
  for (int i = t; i < cntb; i += 256) {
    int e = eb[i];
    int p = atomicAdd(&lc[(unsigned)e >> 24], 1);
    ob[p] = e & 0xFFFFFF;
  }
  __syncthreads();
  for (int i = t; i < cntb; i += 256) cols[base + i] = ob[i];
}

// ---------------------------------------------------------------------------
__device__ inline unsigned short bf16rne(float x) {
  unsigned u = __float_as_uint(x);
  return (unsigned short)((u + 0x7FFFu + ((u >> 16) & 1u)) >> 16);
}
__device__ inline float bf16lo(unsigned q) { return __uint_as_float(q << 16); }
__device__ inline float bf16hi(unsigned q) { return __uint_as_float(q & 0xFFFF0000u); }

// All three W -> hi/lo bf16 plane splits + cur init in ONE launch
__global__ __launch_bounds__(256) void split_w3(const float* __restrict__ W1,
                                                const float* __restrict__ W2,
                                                const float* __restrict__ W3,
                                                unsigned short* __restrict__ w1h,
                                                unsigned short* __restrict__ w1l,
                                                unsigned short* __restrict__ w2h,
                                                unsigned short* __restrict__ w2l,
                                                unsigned short* __restrict__ w3h,
                                                unsigned short* __restrict__ w3l,
                                                int* __restrict__ cur, int B) {
  int i = blockIdx.x * 256 + threadIdx.x;
  const float* W;
  unsigned short *hi, *lo;
  int j;
  if (i < 16384) {
    W = W1; hi = w1h; lo = w1l; j = i;
  } else if (i < 32768) {
    W = W2; hi = w2h; lo = w2l; j = i - 16384;
  } else if (i < 40960) {
    W = W3; hi = w3h; lo = w3l; j = i - 32768;
  } else if (i < 40960 + B) {
    cur[i - 40960] = (i - 40960) * CAP;
    return;
  } else {
    return;
  }
  float v = W[j];
  unsigned short h = bf16rne(v);
  hi[j] = h;
  lo[j] = bf16rne(v - __uint_as_float((unsigned)h << 16));
}

// ---------------------------------------------------------------------------
// GEMM v4: Y[m][c] = bf16( dinv[m] * dot(X[m][:], W[c][:]) ), K=128.
// One block per 64-row m-tile; loops over cc chunks of 64 W rows. A frags
// loaded ONCE into regs; W tile restaged per chunk from L2 (~free).
// ---------------------------------------------------------------------------
#define LDP 136  // padded LDS row stride (bf16): breaks 16-way bank conflict

// Layer 2/3 variant: A from bf16 hi/lo planes in global.
template <int OUTC>
__global__ __launch_bounds__(256) void gemm_planes(const unsigned short* __restrict__ Xh,
                                                   const unsigned short* __restrict__ Xl,
                                                   const unsigned short* __restrict__ Whg,
                                                   const unsigned short* __restrict__ Wlg,
                                                   const float* __restrict__ dinv,
                                                   unsigned short* __restrict__ Y,
                                                   int M) {
  constexpr int CHUNKS = OUTC / 64;
  __shared__ unsigned short Whi[64 * LDP], Wlo[64 * LDP];
  const int tid = threadIdx.x;
  const int m_base = blockIdx.x * 64;
  const int lane = tid & 63;
  const int wv = tid >> 6;
  const int col_l = lane & 15;   // A-row within wave tile / D col
  const int quad = lane >> 4;    // k-quad / D row group
  const size_t arow = (size_t)min(m_base + wv * 16 + col_l, M - 1) * 128;
  const int bBase = col_l * LDP + quad * 8;

  // A fragments: loaded once, reused for all cc chunks
  bfrag aH[4], aL[4];
#pragma unroll
  for (int ks = 0; ks < 4; ++ks) {
    aH[ks] = *(const bfrag*)(Xh + arow + ks * 32 + quad * 8);
    aL[ks] = *(const bfrag*)(Xl + arow + ks * 32 + quad * 8);
  }

  f32x4 acc[CHUNKS][4];
#pragma unroll
  for (int c2 = 0; c2 < CHUNKS; ++c2)
#pragma unroll
    for (int t = 0; t < 4; ++t) acc[c2][t] = {0.f, 0.f, 0.f, 0.f};

#pragma unroll
  for (int c2 = 0; c2 < CHUNKS; ++c2) {
    if (c2) __syncthreads();  // all reads of previous W tile done
    for (int idx = tid; idx < 64 * 16; idx += 256) {
      int r = idx >> 4, g = idx & 15;
      *(u16x8*)(Whi + r * LDP + g * 8) =
          *(const u16x8*)(Whg + (size_t)(c2 * 64 + r) * 128 + g * 8);
      *(u16x8*)(Wlo + r * LDP + g * 8) =
          *(const u16x8*)(Wlg + (size_t)(c2 * 64 + r) * 128 + g * 8);
    }
    __syncthreads();
#pragma unroll
    for (int ks = 0; ks < 4; ++ks) {
#pragma unroll
      for (int t = 0; t < 4; ++t) {
        int bo = bBase + t * 16 * LDP + ks * 32;
        bfrag bHi = *(const bfrag*)(Whi + bo);
        bfrag bLo = *(const bfrag*)(Wlo + bo);
        acc[c2][t] = __builtin_amdgcn_mfma_f32_16x16x32_bf16(aH[ks], bHi, acc[c2][t], 0, 0, 0);
        acc[c2][t] = __builtin_amdgcn_mfma_f32_16x16x32_bf16(aL[ks], bHi, acc[c2][t], 0, 0, 0);
        acc[c2][t] = __builtin_amdgcn_mfma_f32_16x16x32_bf16(aH[ks], bLo, acc[c2][t], 0, 0, 0);
      }
    }
  }

#pragma unroll
  for (int r = 0; r < 4; ++r) {
    int row = m_base + wv * 16 + quad * 4 + r;
    if (row < M) {
      float s = dinv[row];
#pragma unroll
      for (int c2 = 0; c2 < CHUNKS; ++c2)
#pragma unroll
        for (int t = 0; t < 4; ++t) {
          unsigned short h = bf16rne(acc[c2][t][r] * s);
          Y[(size_t)row * OUTC + c2 * 64 + t * 16 + col_l] = h;
        }
    }
  }
}

// Layer-1 variant: A from f32 X, split to hi/lo bf16 in-register.
// Arithmetic identical to the old split_x prepass (h = rne(v), l = rne(v-h)).
template <int OUTC>
__global__ __launch_bounds__(256) void gemm_xsplit(const float* __restrict__ X,
                                                   const unsigned short* __restrict__ Whg,
                                                   const unsigned short* __restrict__ Wlg,
                                                   const float* __restrict__ dinv,
                                                   unsigned short* __restrict__ Y,
                                                   int M) {
  constexpr int CHUNKS = OUTC / 64;
  __shared__ unsigned short Whi[64 * LDP], Wlo[64 * LDP];
  const int tid = threadIdx.x;
  const int m_base = blockIdx.x * 64;
  const int lane = tid & 63;
  const int wv = tid >> 6;
  const int col_l = lane & 15;
  const int quad = lane >> 4;
  const size_t arow = (size_t)min(m_base + wv * 16 + col_l, M - 1) * 128;
  const int bBase = col_l * LDP + quad * 8;

  bfrag aH[4], aL[4];
#pragma unroll
  for (int ks = 0; ks < 4; ++ks) {
    float4 v0 = *(const float4*)(X + arow + ks * 32 + quad * 8);
    float4 v1 = *(const float4*)(X + arow + ks * 32 + quad * 8 + 4);
    float vv[8] = {v0.x, v0.y, v0.z, v0.w, v1.x, v1.y, v1.z, v1.w};
#pragma unroll
    for (int j = 0; j < 8; ++j) {
      unsigned short h = bf16rne(vv[j]);
      aH[ks][j] = (short)h;
      aL[ks][j] = (short)bf16rne(vv[j] - __uint_as_float((unsigned)h << 16));
    }
  }

  f32x4 acc[CHUNKS][4];
#pragma unroll
  for (int c2 = 0; c2 < CHUNKS; ++c2)
#pragma unroll
    for (int t = 0; t < 4; ++t) acc[c2][t] = {0.f, 0.f, 0.f, 0.f};

#pragma unroll
  for (int c2 = 0; c2 < CHUNKS; ++c2) {
    if (c2) __syncthreads();
    for (int idx = tid; idx < 64 * 16; idx += 256) {
      int r = idx >> 4, g = idx & 15;
      *(u16x8*)(Whi + r * LDP + g * 8) =
          *(const u16x8*)(Whg + (size_t)(c2 * 64 + r) * 128 + g * 8);
      *(u16x8*)(Wlo + r * LDP + g * 8) =
          *(const u16x8*)(Wlg + (size_t)(c2 * 64 + r) * 128 + g * 8);
    }
    __syncthreads();
#pragma unroll
    for (int ks = 0; ks < 4; ++ks) {
#pragma unroll
      for (int t = 0; t < 4; ++t) {
        int bo = bBase + t * 16 * LDP + ks * 32;
        bfrag bHi = *(const bfrag*)(Whi + bo);
        bfrag bLo = *(const bfrag*)(Wlo + bo);
        acc[c2][t] = __builtin_amdgcn_mfma_f32_16x16x32_bf16(aH[ks], bHi, acc[c2][t], 0, 0, 0);
        acc[c2][t] = __builtin_amdgcn_mfma_f32_16x16x32_bf16(aL[ks], bHi, acc[c2][t], 0, 0, 0);
        acc[c2][t] = __builtin_amdgcn_mfma_f32_16x16x32_bf16(aH[ks], bLo, acc[c2][t], 0, 0, 0);
      }
    }
  }

#pragma unroll
  for (int r = 0; r < 4; ++r) {
    int row = m_base + wv * 16 + quad * 4 + r;
    if (row < M) {
      float s = dinv[row];
#pragma unroll
      for (int c2 = 0; c2 < CHUNKS; ++c2)
#pragma unroll
        for (int t = 0; t < 4; ++t) {
          unsigned short h = bf16rne(acc[c2][t][r] * s);
          Y[(size_t)row * OUTC + c2 * 64 + t * 16 + col_l] = h;
        }
    }
  }
}

__device__ inline void acc_add(float* a, uint4 d) {
  a[0] += bf16lo(d.x); a[1] += bf16hi(d.x);
  a[2] += bf16lo(d.y); a[3] += bf16hi(d.y);
  a[4] += bf16lo(d.z); a[5] += bf16hi(d.z);
  a[6] += bf16lo(d.w); a[7] += bf16hi(d.w);
}

// ---------------------------------------------------------------------------
// Aggregate v6 (C=128, channel-split): block handles chgroup cg = bid & 7
// (16 channels = 32B/node). Under round-robin block->XCD dispatch, XCD k's
// gather slice = N*32B = 3.2MB -> L2-resident. 2 lanes per node (8ch each),
// 4 edges per chunk in ascending order = v4's add order => bit-identical.
// Always RELU + split-plane output (used for layers 1&2 only).
// ---------------------------------------------------------------------------
__global__ __launch_bounds__(256) void aggregate_cs(const unsigned short* __restrict__ xs,
                                                    const int2* __restrict__ off2,
                                                    const int* __restrict__ cols,
                                                    const float* __restrict__ dinv,
                                                    const float* __restrict__ bias,
                                                    unsigned short* __restrict__ oh,
                                                    unsigned short* __restrict__ ol,
                                                    int N) {
  const int cg = blockIdx.x & 7;        // channel group -> XCD (round-robin)
  const int tile = blockIdx.x >> 3;
  const int t = threadIdx.x;
  const int gl = t & 1;                 // lane within node pair
  const int node = tile * 128 + (t >> 1);
  if (node >= N) return;

  const unsigned co = (unsigned)cg * 32 + (unsigned)gl * 16;  // byte off in row
  const char* xb = (const char*)xs;

  float acc[8];
  {
    // self-loop row (pre-scaled by dinv[node] in the GEMM epilogue)
    uint4 d = *(const uint4*)(xb + (size_t)node * 256 + co);
    acc[0] = bf16lo(d.x); acc[1] = bf16hi(d.x);
    acc[2] = bf16lo(d.y); acc[3] = bf16hi(d.y);
    acc[4] = bf16lo(d.z); acc[5] = bf16hi(d.z);
    acc[6] = bf16lo(d.w); acc[7] = bf16hi(d.w);
  }

  const int2 oo = off2[node];
  const int en = oo.y;
  for (int e0 = oo.x; e0 < en; e0 += 4) {
    // pair loads 4 edge ids: even lane cols[e0,e0+1], odd lane cols[e0+2,e0+3]
    int ca = __builtin_nontemporal_load(&cols[min(e0 + gl * 2,     en - 1)]);
    int cb = __builtin_nontemporal_load(&cols[min(e0 + gl * 2 + 1, en - 1)]);
    int m = en - e0;
    if (m > 4) m = 4;
    int s0 = __shfl(ca, 0, 2);
    int s1 = __shfl(cb, 0, 2);
    int s2 = __shfl(ca, 1, 2);
    int s3 = __shfl(cb, 1, 2);
    uint4 d0 = *(const uint4*)(xb + (size_t)s0 * 256 + co);
    uint4 d1 = *(const uint4*)(xb + (size_t)s1 * 256 + co);
    uint4 d2 = *(const uint4*)(xb + (size_t)s2 * 256 + co);
    uint4 d3 = *(const uint4*)(xb + (size_t)s3 * 256 + co);
    acc_add(acc, d0);                       // m >= 1 always
    if (m > 1) acc_add(acc, d1);
    if (m > 2) acc_add(acc, d2);
    if (m > 3) acc_add(acc, d3);
  }

  const float dd = dinv[node];
  const float4 bA = *(const float4*)(bias + cg * 16 + gl * 8);
  const float4 bB = *(const float4*)(bias + cg * 16 + gl * 8 + 4);
  float h[8];
  h[0] = acc[0] * dd + bA.x; h[1] = acc[1] * dd + bA.y;
  h[2] = acc[2] * dd + bA.z; h[3] = acc[3] * dd + bA.w;
  h[4] = acc[4] * dd + bB.x; h[5] = acc[5] * dd + bB.y;
  h[6] = acc[6] * dd + bB.z; h[7] = acc[7] * dd + bB.w;
#pragma unroll
  for (int q = 0; q < 8; ++q) h[q] = fmaxf(h[q], 0.f);

  u16x8 hv, lv;
#pragma unroll
  for (int q = 0; q < 8; ++q) {
    unsigned short hb = bf16rne(h[q]);
    hv[q] = hb;
    lv[q] = bf16rne(h[q] - __uint_as_float((unsigned)hb << 16));
  }
  const size_t ob = (size_t)node * 128 + cg * 16 + gl * 8;
  __builtin_nontemporal_store(hv, (u16x8*)(oh + ob));
  __builtin_nontemporal_store(lv, (u16x8*)(ol + ob));
}

// ---------------------------------------------------------------------------
// Aggregate v4 (kept for the C=64 final layer).
// ---------------------------------------------------------------------------
template <int C, bool RELU, bool SPLIT>
__global__ __launch_bounds__(256) void aggregate4(const unsigned short* __restrict__ xs,
                                                  const int2* __restrict__ off2,
                                                  const int* __restrict__ cols,
                                                  const float* __restrict__ dinv,
                                                  const float* __restrict__ bias,
                                                  float* __restrict__ outf,
                                                  unsigned short* __restrict__ oh,
                                                  unsigned short* __restrict__ ol,
                                                  int N) {
  constexpr int GL = C / 8;            // lanes per node
  constexpr int LSH = (GL == 16) ? 4 : 3;
  constexpr int NPBk = 256 / GL;       // nodes per block
  const int t = threadIdx.x;
  const int gl = t & (GL - 1);
  const int node = blockIdx.x * NPBk + (t >> LSH);
  if (node >= N) return;

  const unsigned co = (unsigned)gl * 16;  // byte offset of this lane's 8 ch
  const char* xb = (const char*)xs;

  float acc[8];
  {
    uint4 d = *(const uint4*)(xb + (size_t)node * (C * 2) + co);
    acc[0] = bf16lo(d.x); acc[1] = bf16hi(d.x);
    acc[2] = bf16lo(d.y); acc[3] = bf16hi(d.y);
    acc[4] = bf16lo(d.z); acc[5] = bf16hi(d.z);
    acc[6] = bf16lo(d.w); acc[7] = bf16hi(d.w);
  }

  const int2 oo = off2[node];
  const int en = oo.y;
  for (int e0 = oo.x; e0 < en; e0 += GL) {
    int col = __builtin_nontemporal_load(&cols[min(e0 + gl, en - 1)]);
    int m = en - e0;
    if (m > GL) m = GL;
    const int c1 = m - 1;
    for (int j = 0; j < m; j += 4) {
      int s0 = __shfl(col, min(j,     c1), GL);
      int s1 = __shfl(col, min(j + 1, c1), GL);
      int s2 = __shfl(col, min(j + 2, c1), GL);
      int s3 = __shfl(col, min(j + 3, c1), GL);
      uint4 d0 = *(const uint4*)(xb + (size_t)s0 * (C * 2) + co);
      uint4 d1 = *(const uint4*)(xb + (size_t)s1 * (C * 2) + co);
      uint4 d2 = *(const uint4*)(xb + (size_t)s2 * (C * 2) + co);
      uint4 d3 = *(const uint4*)(xb + (size_t)s3 * (C * 2) + co);
      acc_add(acc, d0);                       // j < m always
      if (j + 1 < m) acc_add(acc, d1);
      if (j + 2 < m) acc_add(acc, d2);
      if (j + 3 < m) acc_add(acc, d3);
    }
  }

  const float dd = dinv[node];
  const float4 bA = *(const float4*)(bias + gl * 8);
  const float4 bB = *(const float4*)(bias + gl * 8 + 4);
  float h[8];
  h[0] = acc[0] * dd + bA.x; h[1] = acc[1] * dd + bA.y;
  h[2] = acc[2] * dd + bA.z; h[3] = acc[3] * dd + bA.w;
  h[4] = acc[4] * dd + bB.x; h[5] = acc[5] * dd + bB.y;
  h[6] = acc[6] * dd + bB.z; h[7] = acc[7] * dd + bB.w;
  if (RELU) {
#pragma unroll
    for (int q = 0; q < 8; ++q) h[q] = fmaxf(h[q], 0.f);
  }
  if (SPLIT) {
    u16x8 hv, lv;
#pragma unroll
    for (int q = 0; q < 8; ++q) {
      unsigned short hb = bf16rne(h[q]);
      hv[q] = hb;
      lv[q] = bf16rne(h[q] - __uint_as_float((unsigned)hb << 16));
    }
    __builtin_nontemporal_store(hv, (u16x8*)(oh + (size_t)node * C + gl * 8));
    __builtin_nontemporal_store(lv, (u16x8*)(ol + (size_t)node * C + gl * 8));
  } else {
    f32x4 oA = {h[0], h[1], h[2], h[3]};
    f32x4 oB = {h[4], h[5], h[6], h[7]};
    __builtin_nontemporal_store(oA, (f32x4*)(outf + (size_t)node * C + gl * 8));
    __builtin_nontemporal_store(oB, (f32x4*)(outf + (size_t)node * C + gl * 8 + 4));
  }
}

// ---------------------------------------------------------------------------

extern "C" void kernel_launch(void* const* d_in, const int* in_sizes, int n_in,
                              void* d_out, int out_size, void* d_ws, size_t ws_size,
                              hipStream_t stream) {
  const float* x  = (const float*)d_in[0];
  const int*   ei = (const int*)d_in[1];
  const float* W1 = (const float*)d_in[2];
  const float* b1 = (const float*)d_in[3];
  const float* W2 = (const float*)d_in[4];
  const float* b2 = (const float*)d_in[5];
  const float* W3 = (const float*)d_in[6];
  const float* b3 = (const float*)d_in[7];

  const int N = in_sizes[0] / 128;
  const int E = in_sizes[1] / 2;
  const int* src = ei;
  const int* dst = ei + E;
  const int B = (N + NPB - 1) / NPB;

  char* w = (char*)d_ws;
  size_t p = 0;
  auto alloc = [&](size_t bytes) -> void* {
    void* r = w + p;
    p = (p + bytes + 255) & ~(size_t)255;
    return r;
  };
  float*    dinv   = (float*)alloc((size_t)N * 4);
  int2*     off2   = (int2*)alloc((size_t)N * 8);
  int*      cur    = (int*)alloc((size_t)B * 4);
  int*      binned = (int*)alloc((size_t)B * CAP * 4);
  int*      cols   = (int*)alloc((size_t)B * CAP * 4);
  unsigned short* xsb = (unsigned short*)alloc((size_t)N * 128 * 2);  // GEMM out
  unsigned short* hh  = (unsigned short*)alloc((size_t)N * 128 * 2);  // h hi plane
  unsigned short* hl  = (unsigned short*)alloc((size_t)N * 128 * 2);  // h lo plane
  unsigned short* w1h = (unsigned short*)alloc(128 * 128 * 2);
  unsigned short* w1l = (unsigned short*)alloc(128 * 128 * 2);
  unsigned short* w2h = (unsigned short*)alloc(128 * 128 * 2);
  unsigned short* w2l = (unsigned short*)alloc(128 * 128 * 2);
  unsigned short* w3h = (unsigned short*)alloc(64 * 128 * 2);
  unsigned short* w3l = (unsigned short*)alloc(64 * 128 * 2);

  split_w3<<<(40960 + B + 255) / 256, 256, 0, stream>>>(W1, W2, W3, w1h, w1l,
                                                        w2h, w2l, w3h, w3l,
                                                        cur, B);
  bin_edges<<<BIN_WGS, 256, 0, stream>>>(src, dst, cur, binned, E, B);
  build_buckets<<<B, 256, 0, stream>>>(binned, cur, cols, off2, dinv, N);

  const int gb = (N + 63) / 64;
  const int acs = ((N + 127) / 128) * 8;  // channel-split: 8 cgs per node tile
  const int ab64 = (N + 31) / 32;         // 32 nodes per block (C=64)

  gemm_xsplit<128><<<gb, 256, 0, stream>>>(x, w1h, w1l, dinv, xsb, N);
  aggregate_cs<<<acs, 256, 0, stream>>>(xsb, off2, cols, dinv, b1, hh, hl, N);
  gemm_planes<128><<<gb, 256, 0, stream>>>(hh, hl, w2h, w2l, dinv, xsb, N);
  aggregate_cs<<<acs, 256, 0, stream>>>(xsb, off2, cols, dinv, b2, hh, hl, N);
  gemm_planes<64><<<gb, 256, 0, stream>>>(hh, hl, w3h, w3l, dinv, xsb, N);
  aggregate4<64, false, false><<<ab64, 256, 0, stream>>>(xsb, off2, cols, dinv, b3,
                                                         (float*)d_out, nullptr,
                                                         nullptr, N);
}

// Round 5
// 582.292 us; speedup vs baseline: 1.2109x; 1.2109x over previous
//
#include <hip/hip_runtime.h>

// ---------------------------------------------------------------------------
// 3-layer GCN: out = ReLU(Â(ReLU(Â(Â (X W1^T) +b1) W2^T +b2)) W3^T) +b3
// Â = D^{-1/2}(A+I)D^{-1/2}, deg = in-degree + 1 (self loop).
// Dtype plan: xs (GEMM out) = bf16, CHANNEL-GROUP-MAJOR [cg][N][16ch]; h
// (agg out) = bf16 hi/lo planes [N][128]; GEMM = split-bf16 MFMA.
//
// R16: R15 pm: channel-split with STRIDED slices amplified fetch 4.04x
// (= 128B line / 32B use) and killed L2 residency -> 755MB, 233us. The
// mechanism (line-granularity fetch + residency) is confirmed; fix is a
// physically TRANSPOSED xs layout [cg][node][32B]: XCD k's slice is a
// contiguous N*32B = 3.2MB block < 4MB L2. GEMM epilogue writes this
// layout for free (channel block c2*4+t == a 16-ch group; same 32B store
// segments). Aggregate = R15 v6 byte-identical math, new addressing =>
// bit-identical result. C=64 final layer stays v4.
// ---------------------------------------------------------------------------

#define NPB 256          // nodes per bucket (bucket = dst >> 8)
#define CAP 4672         // edges capacity per bucket region
#define BIN_WGS 512      // workgroups in bin_edges

typedef short bfrag __attribute__((ext_vector_type(8)));       // 8 bf16
typedef float f32x4 __attribute__((ext_vector_type(4)));
typedef unsigned short u16x8 __attribute__((ext_vector_type(8)));

__global__ __launch_bounds__(256) void bin_edges(const int* __restrict__ src,
                                                 const int* __restrict__ dst,
                                                 int* __restrict__ cur,
                                                 int* __restrict__ binned,
                                                 int E, int B) {
  __shared__ int lc[512];
  __shared__ int lbase[512];
  const int t = threadIdx.x;
  const int chunk = (E + BIN_WGS - 1) / BIN_WGS;
  const int e0 = blockIdx.x * chunk;
  const int e1 = min(E, e0 + chunk);

  for (int i = t; i < B; i += 256) lc[i] = 0;
  __syncthreads();
  for (int e = e0 + t; e < e1; e += 256) {
    int d = dst[e];
    atomicAdd(&lc[d >> 8], 1);
  }
  __syncthreads();
  for (int i = t; i < B; i += 256) {
    int c = lc[i];
    lbase[i] = c ? atomicAdd(&cur[i], c) : 0;
    lc[i] = 0;
  }
  __syncthreads();
  for (int e = e0 + t; e < e1; e += 256) {
    int d = dst[e];
    int s = __builtin_nontemporal_load(&src[e]);
    int bk = d >> 8;
    int p = lbase[bk] + atomicAdd(&lc[bk], 1);
    if (p < (bk + 1) * CAP)
      binned[p] = ((d & 255) << 24) | s;
  }
}

__global__ __launch_bounds__(256) void build_buckets(const int* __restrict__ binned,
                                                     const int* __restrict__ cur,
                                                     int* __restrict__ cols,
                                                     int2* __restrict__ off2,
                                                     float* __restrict__ dinv,
                                                     int N) {
  __shared__ int eb[CAP];
  __shared__ int ob[CAP];
  __shared__ int lc[256];
  __shared__ int sc[256];
  const int b = blockIdx.x;
  const int t = threadIdx.x;
  const int base = b * CAP;
  const int cntb = min(cur[b] - base, CAP);

  for (int i = t; i < cntb; i += 256) eb[i] = binned[base + i];
  lc[t] = 0;
  __syncthreads();
  for (int i = t; i < cntb; i += 256)
    atomicAdd(&lc[(unsigned)eb[i] >> 24], 1);
  __syncthreads();
  int myc = lc[t];
  sc[t] = myc;
  __syncthreads();
  for (int d = 1; d < 256; d <<= 1) {
    int a = (t >= d) ? sc[t - d] : 0;
    __syncthreads();
    sc[t] += a;
    __syncthreads();
  }
  int excl = sc[t] - myc;
  int node = b * NPB + t;
  if (node < N) {
    off2[node] = make_int2(base + excl, base + excl + myc);
    dinv[node] = rsqrtf((float)(myc + 1));
  }
  lc[t] = excl;
  __syncthreads();
  for (int i = t; i < cntb; i += 256) {
    int e = eb[i];
    int p = atomicAdd(&lc[(unsigned)e >> 24], 1);
    ob[p] = e & 0xFFFFFF;
  }
  __syncthreads();
  for (int i = t; i < cntb; i += 256) cols[base + i] = ob[i];
}

// ---------------------------------------------------------------------------
__device__ inline unsigned short bf16rne(float x) {
  unsigned u = __float_as_uint(x);
  return (unsigned short)((u + 0x7FFFu + ((u >> 16) & 1u)) >> 16);
}
__device__ inline float bf16lo(unsigned q) { return __uint_as_float(q << 16); }
__device__ inline float bf16hi(unsigned q) { return __uint_as_float(q & 0xFFFF0000u); }

// All three W -> hi/lo bf16 plane splits + cur init in ONE launch
__global__ __launch_bounds__(256) void split_w3(const float* __restrict__ W1,
                                                const float* __restrict__ W2,
                                                const float* __restrict__ W3,
                                                unsigned short* __restrict__ w1h,
                                                unsigned short* __restrict__ w1l,
                                                unsigned short* __restrict__ w2h,
                                                unsigned short* __restrict__ w2l,
                                                unsigned short* __restrict__ w3h,
                                                unsigned short* __restrict__ w3l,
                                                int* __restrict__ cur, int B) {
  int i = blockIdx.x * 256 + threadIdx.x;
  const float* W;
  unsigned short *hi, *lo;
  int j;
  if (i < 16384) {
    W = W1; hi = w1h; lo = w1l; j = i;
  } else if (i < 32768) {
    W = W2; hi = w2h; lo = w2l; j = i - 16384;
  } else if (i < 40960) {
    W = W3; hi = w3h; lo = w3l; j = i - 32768;
  } else if (i < 40960 + B) {
    cur[i - 40960] = (i - 40960) * CAP;
    return;
  } else {
    return;
  }
  float v = W[j];
  unsigned short h = bf16rne(v);
  hi[j] = h;
  lo[j] = bf16rne(v - __uint_as_float((unsigned)h << 16));
}

// ---------------------------------------------------------------------------
// GEMM v5: Y[m][c] = bf16( dinv[m] * dot(X[m][:], W[c][:]) ), K=128.
// One block per 64-row m-tile; loops over cc chunks of 64 W rows. A frags
// loaded once into regs; W tile restaged per chunk from L2 (~free).
// CSOUT: write channel-group-major layout Y[(cg*M + row)*16 + col_l],
// cg = c2*4 + t (a 16-channel group). Same 32B store segments as standard.
// ---------------------------------------------------------------------------
#define LDP 136  // padded LDS row stride (bf16): breaks 16-way bank conflict

// Layer 2/3 variant: A from bf16 hi/lo planes in global.
template <int OUTC, bool CSOUT>
__global__ __launch_bounds__(256) void gemm_planes(const unsigned short* __restrict__ Xh,
                                                   const unsigned short* __restrict__ Xl,
                                                   const unsigned short* __restrict__ Whg,
                                                   const unsigned short* __restrict__ Wlg,
                                                   const float* __restrict__ dinv,
                                                   unsigned short* __restrict__ Y,
                                                   int M) {
  constexpr int CHUNKS = OUTC / 64;
  __shared__ unsigned short Whi[64 * LDP], Wlo[64 * LDP];
  const int tid = threadIdx.x;
  const int m_base = blockIdx.x * 64;
  const int lane = tid & 63;
  const int wv = tid >> 6;
  const int col_l = lane & 15;   // A-row within wave tile / D col
  const int quad = lane >> 4;    // k-quad / D row group
  const size_t arow = (size_t)min(m_base + wv * 16 + col_l, M - 1) * 128;
  const int bBase = col_l * LDP + quad * 8;

  // A fragments: loaded once, reused for all cc chunks
  bfrag aH[4], aL[4];
#pragma unroll
  for (int ks = 0; ks < 4; ++ks) {
    aH[ks] = *(const bfrag*)(Xh + arow + ks * 32 + quad * 8);
    aL[ks] = *(const bfrag*)(Xl + arow + ks * 32 + quad * 8);
  }

  f32x4 acc[CHUNKS][4];
#pragma unroll
  for (int c2 = 0; c2 < CHUNKS; ++c2)
#pragma unroll
    for (int t = 0; t < 4; ++t) acc[c2][t] = {0.f, 0.f, 0.f, 0.f};

#pragma unroll
  for (int c2 = 0; c2 < CHUNKS; ++c2) {
    if (c2) __syncthreads();  // all reads of previous W tile done
    for (int idx = tid; idx < 64 * 16; idx += 256) {
      int r = idx >> 4, g = idx & 15;
      *(u16x8*)(Whi + r * LDP + g * 8) =
          *(const u16x8*)(Whg + (size_t)(c2 * 64 + r) * 128 + g * 8);
      *(u16x8*)(Wlo + r * LDP + g * 8) =
          *(const u16x8*)(Wlg + (size_t)(c2 * 64 + r) * 128 + g * 8);
    }
    __syncthreads();
#pragma unroll
    for (int ks = 0; ks < 4; ++ks) {
#pragma unroll
      for (int t = 0; t < 4; ++t) {
        int bo = bBase + t * 16 * LDP + ks * 32;
        bfrag bHi = *(const bfrag*)(Whi + bo);
        bfrag bLo = *(const bfrag*)(Wlo + bo);
        acc[c2][t] = __builtin_amdgcn_mfma_f32_16x16x32_bf16(aH[ks], bHi, acc[c2][t], 0, 0, 0);
        acc[c2][t] = __builtin_amdgcn_mfma_f32_16x16x32_bf16(aL[ks], bHi, acc[c2][t], 0, 0, 0);
        acc[c2][t] = __builtin_amdgcn_mfma_f32_16x16x32_bf16(aH[ks], bLo, acc[c2][t], 0, 0, 0);
      }
    }
  }

#pragma unroll
  for (int r = 0; r < 4; ++r) {
    int row = m_base + wv * 16 + quad * 4 + r;
    if (row < M) {
      float s = dinv[row];
#pragma unroll
      for (int c2 = 0; c2 < CHUNKS; ++c2)
#pragma unroll
        for (int t = 0; t < 4; ++t) {
          unsigned short h = bf16rne(acc[c2][t][r] * s);
          if (CSOUT)
            Y[((size_t)(c2 * 4 + t) * M + row) * 16 + col_l] = h;
          else
            Y[(size_t)row * OUTC + c2 * 64 + t * 16 + col_l] = h;
        }
    }
  }
}

// Layer-1 variant: A from f32 X, split to hi/lo bf16 in-register.
template <int OUTC, bool CSOUT>
__global__ __launch_bounds__(256) void gemm_xsplit(const float* __restrict__ X,
                                                   const unsigned short* __restrict__ Whg,
                                                   const unsigned short* __restrict__ Wlg,
                                                   const float* __restrict__ dinv,
                                                   unsigned short* __restrict__ Y,
                                                   int M) {
  constexpr int CHUNKS = OUTC / 64;
  __shared__ unsigned short Whi[64 * LDP], Wlo[64 * LDP];
  const int tid = threadIdx.x;
  const int m_base = blockIdx.x * 64;
  const int lane = tid & 63;
  const int wv = tid >> 6;
  const int col_l = lane & 15;
  const int quad = lane >> 4;
  const size_t arow = (size_t)min(m_base + wv * 16 + col_l, M - 1) * 128;
  const int bBase = col_l * LDP + quad * 8;

  bfrag aH[4], aL[4];
#pragma unroll
  for (int ks = 0; ks < 4; ++ks) {
    float4 v0 = *(const float4*)(X + arow + ks * 32 + quad * 8);
    float4 v1 = *(const float4*)(X + arow + ks * 32 + quad * 8 + 4);
    float vv[8] = {v0.x, v0.y, v0.z, v0.w, v1.x, v1.y, v1.z, v1.w};
#pragma unroll
    for (int j = 0; j < 8; ++j) {
      unsigned short h = bf16rne(vv[j]);
      aH[ks][j] = (short)h;
      aL[ks][j] = (short)bf16rne(vv[j] - __uint_as_float((unsigned)h << 16));
    }
  }

  f32x4 acc[CHUNKS][4];
#pragma unroll
  for (int c2 = 0; c2 < CHUNKS; ++c2)
#pragma unroll
    for (int t = 0; t < 4; ++t) acc[c2][t] = {0.f, 0.f, 0.f, 0.f};

#pragma unroll
  for (int c2 = 0; c2 < CHUNKS; ++c2) {
    if (c2) __syncthreads();
    for (int idx = tid; idx < 64 * 16; idx += 256) {
      int r = idx >> 4, g = idx & 15;
      *(u16x8*)(Whi + r * LDP + g * 8) =
          *(const u16x8*)(Whg + (size_t)(c2 * 64 + r) * 128 + g * 8);
      *(u16x8*)(Wlo + r * LDP + g * 8) =
          *(const u16x8*)(Wlg + (size_t)(c2 * 64 + r) * 128 + g * 8);
    }
    __syncthreads();
#pragma unroll
    for (int ks = 0; ks < 4; ++ks) {
#pragma unroll
      for (int t = 0; t < 4; ++t) {
        int bo = bBase + t * 16 * LDP + ks * 32;
        bfrag bHi = *(const bfrag*)(Whi + bo);
        bfrag bLo = *(const bfrag*)(Wlo + bo);
        acc[c2][t] = __builtin_amdgcn_mfma_f32_16x16x32_bf16(aH[ks], bHi, acc[c2][t], 0, 0, 0);
        acc[c2][t] = __builtin_amdgcn_mfma_f32_16x16x32_bf16(aL[ks], bHi, acc[c2][t], 0, 0, 0);
        acc[c2][t] = __builtin_amdgcn_mfma_f32_16x16x32_bf16(aH[ks], bLo, acc[c2][t], 0, 0, 0);
      }
    }
  }

#pragma unroll
  for (int r = 0; r < 4; ++r) {
    int row = m_base + wv * 16 + quad * 4 + r;
    if (row < M) {
      float s = dinv[row];
#pragma unroll
      for (int c2 = 0; c2 < CHUNKS; ++c2)
#pragma unroll
        for (int t = 0; t < 4; ++t) {
          unsigned short h = bf16rne(acc[c2][t][r] * s);
          if (CSOUT)
            Y[((size_t)(c2 * 4 + t) * M + row) * 16 + col_l] = h;
          else
            Y[(size_t)row * OUTC + c2 * 64 + t * 16 + col_l] = h;
        }
    }
  }
}

__device__ inline void acc_add(float* a, uint4 d) {
  a[0] += bf16lo(d.x); a[1] += bf16hi(d.x);
  a[2] += bf16lo(d.y); a[3] += bf16hi(d.y);
  a[4] += bf16lo(d.z); a[5] += bf16hi(d.z);
  a[6] += bf16lo(d.w); a[7] += bf16hi(d.w);
}

// ---------------------------------------------------------------------------
// Aggregate v7 (C=128, channel-split, cg-major xs): block handles chgroup
// cg = bid & 7; xs slice [cg][N][32B] is a CONTIGUOUS 3.2MB block -> L2-
// resident on the XCD that owns cg (round-robin dispatch). 2 lanes/node,
// 4 edges/chunk ascending = v4/v6 add order => bit-identical result.
// Output: bf16 hi/lo planes in standard [N][128] layout (GEMM A input).
// ---------------------------------------------------------------------------
__global__ __launch_bounds__(256) void aggregate_cs(const unsigned short* __restrict__ xs,
                                                    const int2* __restrict__ off2,
                                                    const int* __restrict__ cols,
                                                    const float* __restrict__ dinv,
                                                    const float* __restrict__ bias,
                                                    unsigned short* __restrict__ oh,
                                                    unsigned short* __restrict__ ol,
                                                    int N) {
  const int cg = blockIdx.x & 7;        // channel group -> XCD (round-robin)
  const int tile = blockIdx.x >> 3;
  const int t = threadIdx.x;
  const int gl = t & 1;                 // lane within node pair
  const int node = tile * 128 + (t >> 1);
  if (node >= N) return;

  // cg-major slice: byte base of this cg's [N][32B] block
  const char* xb = (const char*)xs + (size_t)cg * N * 32;
  const unsigned go = (unsigned)gl * 16;

  float acc[8];
  {
    // self-loop row (pre-scaled by dinv[node] in the GEMM epilogue)
    uint4 d = *(const uint4*)(xb + (size_t)node * 32 + go);
    acc[0] = bf16lo(d.x); acc[1] = bf16hi(d.x);
    acc[2] = bf16lo(d.y); acc[3] = bf16hi(d.y);
    acc[4] = bf16lo(d.z); acc[5] = bf16hi(d.z);
    acc[6] = bf16lo(d.w); acc[7] = bf16hi(d.w);
  }

  const int2 oo = off2[node];
  const int en = oo.y;
  for (int e0 = oo.x; e0 < en; e0 += 4) {
    // pair loads 4 edge ids: even lane cols[e0,e0+1], odd lane cols[e0+2,e0+3]
    int ca = __builtin_nontemporal_load(&cols[min(e0 + gl * 2,     en - 1)]);
    int cb = __builtin_nontemporal_load(&cols[min(e0 + gl * 2 + 1, en - 1)]);
    int m = en - e0;
    if (m > 4) m = 4;
    int s0 = __shfl(ca, 0, 2);
    int s1 = __shfl(cb, 0, 2);
    int s2 = __shfl(ca, 1, 2);
    int s3 = __shfl(cb, 1, 2);
    uint4 d0 = *(const uint4*)(xb + (size_t)s0 * 32 + go);
    uint4 d1 = *(const uint4*)(xb + (size_t)s1 * 32 + go);
    uint4 d2 = *(const uint4*)(xb + (size_t)s2 * 32 + go);
    uint4 d3 = *(const uint4*)(xb + (size_t)s3 * 32 + go);
    acc_add(acc, d0);                       // m >= 1 always
    if (m > 1) acc_add(acc, d1);
    if (m > 2) acc_add(acc, d2);
    if (m > 3) acc_add(acc, d3);
  }

  const float dd = dinv[node];
  const float4 bA = *(const float4*)(bias + cg * 16 + gl * 8);
  const float4 bB = *(const float4*)(bias + cg * 16 + gl * 8 + 4);
  float h[8];
  h[0] = acc[0] * dd + bA.x; h[1] = acc[1] * dd + bA.y;
  h[2] = acc[2] * dd + bA.z; h[3] = acc[3] * dd + bA.w;
  h[4] = acc[4] * dd + bB.x; h[5] = acc[5] * dd + bB.y;
  h[6] = acc[6] * dd + bB.z; h[7] = acc[7] * dd + bB.w;
#pragma unroll
  for (int q = 0; q < 8; ++q) h[q] = fmaxf(h[q], 0.f);

  u16x8 hv, lv;
#pragma unroll
  for (int q = 0; q < 8; ++q) {
    unsigned short hb = bf16rne(h[q]);
    hv[q] = hb;
    lv[q] = bf16rne(h[q] - __uint_as_float((unsigned)hb << 16));
  }
  const size_t ob = (size_t)node * 128 + cg * 16 + gl * 8;
  __builtin_nontemporal_store(hv, (u16x8*)(oh + ob));
  __builtin_nontemporal_store(lv, (u16x8*)(ol + ob));
}

// ---------------------------------------------------------------------------
// Aggregate v4 (kept for the C=64 final layer; standard [N][64] xs layout).
// ---------------------------------------------------------------------------
template <int C, bool RELU, bool SPLIT>
__global__ __launch_bounds__(256) void aggregate4(const unsigned short* __restrict__ xs,
                                                  const int2* __restrict__ off2,
                                                  const int* __restrict__ cols,
                                                  const float* __restrict__ dinv,
                                                  const float* __restrict__ bias,
                                                  float* __restrict__ outf,
                                                  unsigned short* __restrict__ oh,
                                                  unsigned short* __restrict__ ol,
                                                  int N) {
  constexpr int GL = C / 8;            // lanes per node
  constexpr int LSH = (GL == 16) ? 4 : 3;
  constexpr int NPBk = 256 / GL;       // nodes per block
  const int t = threadIdx.x;
  const int gl = t & (GL - 1);
  const int node = blockIdx.x * NPBk + (t >> LSH);
  if (node >= N) return;

  const unsigned co = (unsigned)gl * 16;  // byte offset of this lane's 8 ch
  const char* xb = (const char*)xs;

  float acc[8];
  {
    uint4 d = *(const uint4*)(xb + (size_t)node * (C * 2) + co);
    acc[0] = bf16lo(d.x); acc[1] = bf16hi(d.x);
    acc[2] = bf16lo(d.y); acc[3] = bf16hi(d.y);
    acc[4] = bf16lo(d.z); acc[5] = bf16hi(d.z);
    acc[6] = bf16lo(d.w); acc[7] = bf16hi(d.w);
  }

  const int2 oo = off2[node];
  const int en = oo.y;
  for (int e0 = oo.x; e0 < en; e0 += GL) {
    int col = __builtin_nontemporal_load(&cols[min(e0 + gl, en - 1)]);
    int m = en - e0;
    if (m > GL) m = GL;
    const int c1 = m - 1;
    for (int j = 0; j < m; j += 4) {
      int s0 = __shfl(col, min(j,     c1), GL);
      int s1 = __shfl(col, min(j + 1, c1), GL);
      int s2 = __shfl(col, min(j + 2, c1), GL);
      int s3 = __shfl(col, min(j + 3, c1), GL);
      uint4 d0 = *(const uint4*)(xb + (size_t)s0 * (C * 2) + co);
      uint4 d1 = *(const uint4*)(xb + (size_t)s1 * (C * 2) + co);
      uint4 d2 = *(const uint4*)(xb + (size_t)s2 * (C * 2) + co);
      uint4 d3 = *(const uint4*)(xb + (size_t)s3 * (C * 2) + co);
      acc_add(acc, d0);                       // j < m always
      if (j + 1 < m) acc_add(acc, d1);
      if (j + 2 < m) acc_add(acc, d2);
      if (j + 3 < m) acc_add(acc, d3);
    }
  }

  const float dd = dinv[node];
  const float4 bA = *(const float4*)(bias + gl * 8);
  const float4 bB = *(const float4*)(bias + gl * 8 + 4);
  float h[8];
  h[0] = acc[0] * dd + bA.x; h[1] = acc[1] * dd + bA.y;
  h[2] = acc[2] * dd + bA.z; h[3] = acc[3] * dd + bA.w;
  h[4] = acc[4] * dd + bB.x; h[5] = acc[5] * dd + bB.y;
  h[6] = acc[6] * dd + bB.z; h[7] = acc[7] * dd + bB.w;
  if (RELU) {
#pragma unroll
    for (int q = 0; q < 8; ++q) h[q] = fmaxf(h[q], 0.f);
  }
  if (SPLIT) {
    u16x8 hv, lv;
#pragma unroll
    for (int q = 0; q < 8; ++q) {
      unsigned short hb = bf16rne(h[q]);
      hv[q] = hb;
      lv[q] = bf16rne(h[q] - __uint_as_float((unsigned)hb << 16));
    }
    __builtin_nontemporal_store(hv, (u16x8*)(oh + (size_t)node * C + gl * 8));
    __builtin_nontemporal_store(lv, (u16x8*)(ol + (size_t)node * C + gl * 8));
  } else {
    f32x4 oA = {h[0], h[1], h[2], h[3]};
    f32x4 oB = {h[4], h[5], h[6], h[7]};
    __builtin_nontemporal_store(oA, (f32x4*)(outf + (size_t)node * C + gl * 8));
    __builtin_nontemporal_store(oB, (f32x4*)(outf + (size_t)node * C + gl * 8 + 4));
  }
}

// ---------------------------------------------------------------------------

extern "C" void kernel_launch(void* const* d_in, const int* in_sizes, int n_in,
                              void* d_out, int out_size, void* d_ws, size_t ws_size,
                              hipStream_t stream) {
  const float* x  = (const float*)d_in[0];
  const int*   ei = (const int*)d_in[1];
  const float* W1 = (const float*)d_in[2];
  const float* b1 = (const float*)d_in[3];
  const float* W2 = (const float*)d_in[4];
  const float* b2 = (const float*)d_in[5];
  const float* W3 = (const float*)d_in[6];
  const float* b3 = (const float*)d_in[7];

  const int N = in_sizes[0] / 128;
  const int E = in_sizes[1] / 2;
  const int* src = ei;
  const int* dst = ei + E;
  const int B = (N + NPB - 1) / NPB;

  char* w = (char*)d_ws;
  size_t p = 0;
  auto alloc = [&](size_t bytes) -> void* {
    void* r = w + p;
    p = (p + bytes + 255) & ~(size_t)255;
    return r;
  };
  float*    dinv   = (float*)alloc((size_t)N * 4);
  int2*     off2   = (int2*)alloc((size_t)N * 8);
  int*      cur    = (int*)alloc((size_t)B * 4);
  int*      binned = (int*)alloc((size_t)B * CAP * 4);
  int*      cols   = (int*)alloc((size_t)B * CAP * 4);
  unsigned short* xsb = (unsigned short*)alloc((size_t)N * 128 * 2);  // GEMM out
  unsigned short* hh  = (unsigned short*)alloc((size_t)N * 128 * 2);  // h hi plane
  unsigned short* hl  = (unsigned short*)alloc((size_t)N * 128 * 2);  // h lo plane
  unsigned short* w1h = (unsigned short*)alloc(128 * 128 * 2);
  unsigned short* w1l = (unsigned short*)alloc(128 * 128 * 2);
  unsigned short* w2h = (unsigned short*)alloc(128 * 128 * 2);
  unsigned short* w2l = (unsigned short*)alloc(128 * 128 * 2);
  unsigned short* w3h = (unsigned short*)alloc(64 * 128 * 2);
  unsigned short* w3l = (unsigned short*)alloc(64 * 128 * 2);

  split_w3<<<(40960 + B + 255) / 256, 256, 0, stream>>>(W1, W2, W3, w1h, w1l,
                                                        w2h, w2l, w3h, w3l,
                                                        cur, B);
  bin_edges<<<BIN_WGS, 256, 0, stream>>>(src, dst, cur, binned, E, B);
  build_buckets<<<B, 256, 0, stream>>>(binned, cur, cols, off2, dinv, N);

  const int gb = (N + 63) / 64;
  const int acs = ((N + 127) / 128) * 8;  // channel-split: 8 cgs per node tile
  const int ab64 = (N + 31) / 32;         // 32 nodes per block (C=64)

  gemm_xsplit<128, true><<<gb, 256, 0, stream>>>(x, w1h, w1l, dinv, xsb, N);
  aggregate_cs<<<acs, 256, 0, stream>>>(xsb, off2, cols, dinv, b1, hh, hl, N);
  gemm_planes<128, true><<<gb, 256, 0, stream>>>(hh, hl, w2h, w2l, dinv, xsb, N);
  aggregate_cs<<<acs, 256, 0, stream>>>(xsb, off2, cols, dinv, b2, hh, hl, N);
  gemm_planes<64, false><<<gb, 256, 0, stream>>>(hh, hl, w3h, w3l, dinv, xsb, N);
  aggregate4<64, false, false><<<ab64, 256, 0, stream>>>(xsb, off2, cols, dinv, b3,
                                                         (float*)d_out, nullptr,
                                                         nullptr, N);
}

// Round 6
// 376.237 us; speedup vs baseline: 1.8740x; 1.5477x over previous
//
#include <hip/hip_runtime.h>

// ---------------------------------------------------------------------------
// 3-layer GCN: out = ReLU(Â(ReLU(Â(Â (X W1^T) +b1) W2^T +b2)) W3^T) +b3
// Â = D^{-1/2}(A+I)D^{-1/2}, deg = in-degree + 1 (self loop).
//
// R17: cg=2 half-row channel split for the C=128 aggregates.
// R15/R16 pm established: fetch = per-XCD-slice x 8 (L3 does NOT absorb
// cross-XCD re-reads); request efficiency must stay >=128B-used per line
// and ~8 line-req/wave-inst (v4 profile) or TA-issue binds (cs: 171us at
// 32 lines/inst); v4 sits at the random-granule HBM ceiling (3.65 TB/s,
// depth-invariant). cg=2: xs stored [cg][node][64ch]; cg = bid&1 + round-
// robin dispatch -> each XCD reads ONE contiguous 12.8MB slice. Fetch
// 187->~130MB at v4's exact request profile (8 lanes share one 128B line).
// GEMM epilogue writes the layout free (cg==c2). 8-edge chunks reorder f32
// adds vs v4's 16-edge chunks: ~2^-24 noise, invisible vs 2^-10 bf16 floor.
// ---------------------------------------------------------------------------

#define NPB 256          // nodes per bucket (bucket = dst >> 8)
#define CAP 4672         // edges capacity per bucket region
#define BIN_WGS 512      // workgroups in bin_edges

typedef short bfrag __attribute__((ext_vector_type(8)));       // 8 bf16
typedef float f32x4 __attribute__((ext_vector_type(4)));
typedef unsigned short u16x8 __attribute__((ext_vector_type(8)));

__global__ __launch_bounds__(256) void bin_edges(const int* __restrict__ src,
                                                 const int* __restrict__ dst,
                                                 int* __restrict__ cur,
                                                 int* __restrict__ binned,
                                                 int E, int B) {
  __shared__ int lc[512];
  __shared__ int lbase[512];
  const int t = threadIdx.x;
  const int chunk = (E + BIN_WGS - 1) / BIN_WGS;
  const int e0 = blockIdx.x * chunk;
  const int e1 = min(E, e0 + chunk);

  for (int i = t; i < B; i += 256) lc[i] = 0;
  __syncthreads();
  for (int e = e0 + t; e < e1; e += 256) {
    int d = dst[e];
    atomicAdd(&lc[d >> 8], 1);
  }
  __syncthreads();
  for (int i = t; i < B; i += 256) {
    int c = lc[i];
    lbase[i] = c ? atomicAdd(&cur[i], c) : 0;
    lc[i] = 0;
  }
  __syncthreads();
  for (int e = e0 + t; e < e1; e += 256) {
    int d = dst[e];
    int s = __builtin_nontemporal_load(&src[e]);
    int bk = d >> 8;
    int p = lbase[bk] + atomicAdd(&lc[bk], 1);
    if (p < (bk + 1) * CAP)
      binned[p] = ((d & 255) << 24) | s;
  }
}

__global__ __launch_bounds__(256) void build_buckets(const int* __restrict__ binned,
                                                     const int* __restrict__ cur,
                                                     int* __restrict__ cols,
                                                     int2* __restrict__ off2,
                                                     float* __restrict__ dinv,
                                                     int N) {
  __shared__ int eb[CAP];
  __shared__ int ob[CAP];
  __shared__ int lc[256];
  __shared__ int sc[256];
  const int b = blockIdx.x;
  const int t = threadIdx.x;
  const int base = b * CAP;
  const int cntb = min(cur[b] - base, CAP);

  for (int i = t; i < cntb; i += 256) eb[i] = binned[base + i];
  lc[t] = 0;
  __syncthreads();
  for (int i = t; i < cntb; i += 256)
    atomicAdd(&lc[(unsigned)eb[i] >> 24], 1);
  __syncthreads();
  int myc = lc[t];
  sc[t] = myc;
  __syncthreads();
  for (int d = 1; d < 256; d <<= 1) {
    int a = (t >= d) ? sc[t - d] : 0;
    __syncthreads();
    sc[t] += a;
    __syncthreads();
  }
  int excl = sc[t] - myc;
  int node = b * NPB + t;
  if (node < N) {
    off2[node] = make_int2(base + excl, base + excl + myc);
    dinv[node] = rsqrtf((float)(myc + 1));
  }
  lc[t] = excl;
  __syncthreads();
  for (int i = t; i < cntb; i += 256) {
    int e = eb[i];
    int p = atomicAdd(&lc[(unsigned)e >> 24], 1);
    ob[p] = e & 0xFFFFFF;
  }
  __syncthreads();
  for (int i = t; i < cntb; i += 256) cols[base + i] = ob[i];
}

// ---------------------------------------------------------------------------
__device__ inline unsigned short bf16rne(float x) {
  unsigned u = __float_as_uint(x);
  return (unsigned short)((u + 0x7FFFu + ((u >> 16) & 1u)) >> 16);
}
__device__ inline float bf16lo(unsigned q) { return __uint_as_float(q << 16); }
__device__ inline float bf16hi(unsigned q) { return __uint_as_float(q & 0xFFFF0000u); }

// All three W -> hi/lo bf16 plane splits + cur init in ONE launch
__global__ __launch_bounds__(256) void split_w3(const float* __restrict__ W1,
                                                const float* __restrict__ W2,
                                                const float* __restrict__ W3,
                                                unsigned short* __restrict__ w1h,
                                                unsigned short* __restrict__ w1l,
                                                unsigned short* __restrict__ w2h,
                                                unsigned short* __restrict__ w2l,
                                                unsigned short* __restrict__ w3h,
                                                unsigned short* __restrict__ w3l,
                                                int* __restrict__ cur, int B) {
  int i = blockIdx.x * 256 + threadIdx.x;
  const float* W;
  unsigned short *hi, *lo;
  int j;
  if (i < 16384) {
    W = W1; hi = w1h; lo = w1l; j = i;
  } else if (i < 32768) {
    W = W2; hi = w2h; lo = w2l; j = i - 16384;
  } else if (i < 40960) {
    W = W3; hi = w3h; lo = w3l; j = i - 32768;
  } else if (i < 40960 + B) {
    cur[i - 40960] = (i - 40960) * CAP;
    return;
  } else {
    return;
  }
  float v = W[j];
  unsigned short h = bf16rne(v);
  hi[j] = h;
  lo[j] = bf16rne(v - __uint_as_float((unsigned)h << 16));
}

// ---------------------------------------------------------------------------
// GEMM: Y[m][c] = bf16( dinv[m] * dot(X[m][:], W[c][:]) ), K=128.
// One block per 64-row m-tile; loops over cc chunks of 64 W rows. A frags
// loaded once into regs; W tile restaged per chunk from L2 (~free).
// CSOUT: write half-row-major layout Y[(c2*M + row)*64 + t*16 + col_l]
// (cg == c2: channels c2*64..c2*64+63 form one contiguous 128B half-row).
// ---------------------------------------------------------------------------
#define LDP 136  // padded LDS row stride (bf16): breaks 16-way bank conflict

// Layer 2/3 variant: A from bf16 hi/lo planes in global.
template <int OUTC, bool CSOUT>
__global__ __launch_bounds__(256) void gemm_planes(const unsigned short* __restrict__ Xh,
                                                   const unsigned short* __restrict__ Xl,
                                                   const unsigned short* __restrict__ Whg,
                                                   const unsigned short* __restrict__ Wlg,
                                                   const float* __restrict__ dinv,
                                                   unsigned short* __restrict__ Y,
                                                   int M) {
  constexpr int CHUNKS = OUTC / 64;
  __shared__ unsigned short Whi[64 * LDP], Wlo[64 * LDP];
  const int tid = threadIdx.x;
  const int m_base = blockIdx.x * 64;
  const int lane = tid & 63;
  const int wv = tid >> 6;
  const int col_l = lane & 15;   // A-row within wave tile / D col
  const int quad = lane >> 4;    // k-quad / D row group
  const size_t arow = (size_t)min(m_base + wv * 16 + col_l, M - 1) * 128;
  const int bBase = col_l * LDP + quad * 8;

  // A fragments: loaded once, reused for all cc chunks
  bfrag aH[4], aL[4];
#pragma unroll
  for (int ks = 0; ks < 4; ++ks) {
    aH[ks] = *(const bfrag*)(Xh + arow + ks * 32 + quad * 8);
    aL[ks] = *(const bfrag*)(Xl + arow + ks * 32 + quad * 8);
  }

  f32x4 acc[CHUNKS][4];
#pragma unroll
  for (int c2 = 0; c2 < CHUNKS; ++c2)
#pragma unroll
    for (int t = 0; t < 4; ++t) acc[c2][t] = {0.f, 0.f, 0.f, 0.f};

#pragma unroll
  for (int c2 = 0; c2 < CHUNKS; ++c2) {
    if (c2) __syncthreads();  // all reads of previous W tile done
    for (int idx = tid; idx < 64 * 16; idx += 256) {
      int r = idx >> 4, g = idx & 15;
      *(u16x8*)(Whi + r * LDP + g * 8) =
          *(const u16x8*)(Whg + (size_t)(c2 * 64 + r) * 128 + g * 8);
      *(u16x8*)(Wlo + r * LDP + g * 8) =
          *(const u16x8*)(Wlg + (size_t)(c2 * 64 + r) * 128 + g * 8);
    }
    __syncthreads();
#pragma unroll
    for (int ks = 0; ks < 4; ++ks) {
#pragma unroll
      for (int t = 0; t < 4; ++t) {
        int bo = bBase + t * 16 * LDP + ks * 32;
        bfrag bHi = *(const bfrag*)(Whi + bo);
        bfrag bLo = *(const bfrag*)(Wlo + bo);
        acc[c2][t] = __builtin_amdgcn_mfma_f32_16x16x32_bf16(aH[ks], bHi, acc[c2][t], 0, 0, 0);
        acc[c2][t] = __builtin_amdgcn_mfma_f32_16x16x32_bf16(aL[ks], bHi, acc[c2][t], 0, 0, 0);
        acc[c2][t] = __builtin_amdgcn_mfma_f32_16x16x32_bf16(aH[ks], bLo, acc[c2][t], 0, 0, 0);
      }
    }
  }

#pragma unroll
  for (int r = 0; r < 4; ++r) {
    int row = m_base + wv * 16 + quad * 4 + r;
    if (row < M) {
      float s = dinv[row];
#pragma unroll
      for (int c2 = 0; c2 < CHUNKS; ++c2)
#pragma unroll
        for (int t = 0; t < 4; ++t) {
          unsigned short h = bf16rne(acc[c2][t][r] * s);
          if (CSOUT)
            Y[((size_t)c2 * M + row) * 64 + t * 16 + col_l] = h;
          else
            Y[(size_t)row * OUTC + c2 * 64 + t * 16 + col_l] = h;
        }
    }
  }
}

// Layer-1 variant: A from f32 X, split to hi/lo bf16 in-register.
template <int OUTC, bool CSOUT>
__global__ __launch_bounds__(256) void gemm_xsplit(const float* __restrict__ X,
                                                   const unsigned short* __restrict__ Whg,
                                                   const unsigned short* __restrict__ Wlg,
                                                   const float* __restrict__ dinv,
                                                   unsigned short* __restrict__ Y,
                                                   int M) {
  constexpr int CHUNKS = OUTC / 64;
  __shared__ unsigned short Whi[64 * LDP], Wlo[64 * LDP];
  const int tid = threadIdx.x;
  const int m_base = blockIdx.x * 64;
  const int lane = tid & 63;
  const int wv = tid >> 6;
  const int col_l = lane & 15;
  const int quad = lane >> 4;
  const size_t arow = (size_t)min(m_base + wv * 16 + col_l, M - 1) * 128;
  const int bBase = col_l * LDP + quad * 8;

  bfrag aH[4], aL[4];
#pragma unroll
  for (int ks = 0; ks < 4; ++ks) {
    float4 v0 = *(const float4*)(X + arow + ks * 32 + quad * 8);
    float4 v1 = *(const float4*)(X + arow + ks * 32 + quad * 8 + 4);
    float vv[8] = {v0.x, v0.y, v0.z, v0.w, v1.x, v1.y, v1.z, v1.w};
#pragma unroll
    for (int j = 0; j < 8; ++j) {
      unsigned short h = bf16rne(vv[j]);
      aH[ks][j] = (short)h;
      aL[ks][j] = (short)bf16rne(vv[j] - __uint_as_float((unsigned)h << 16));
    }
  }

  f32x4 acc[CHUNKS][4];
#pragma unroll
  for (int c2 = 0; c2 < CHUNKS; ++c2)
#pragma unroll
    for (int t = 0; t < 4; ++t) acc[c2][t] = {0.f, 0.f, 0.f, 0.f};

#pragma unroll
  for (int c2 = 0; c2 < CHUNKS; ++c2) {
    if (c2) __syncthreads();
    for (int idx = tid; idx < 64 * 16; idx += 256) {
      int r = idx >> 4, g = idx & 15;
      *(u16x8*)(Whi + r * LDP + g * 8) =
          *(const u16x8*)(Whg + (size_t)(c2 * 64 + r) * 128 + g * 8);
      *(u16x8*)(Wlo + r * LDP + g * 8) =
          *(const u16x8*)(Wlg + (size_t)(c2 * 64 + r) * 128 + g * 8);
    }
    __syncthreads();
#pragma unroll
    for (int ks = 0; ks < 4; ++ks) {
#pragma unroll
      for (int t = 0; t < 4; ++t) {
        int bo = bBase + t * 16 * LDP + ks * 32;
        bfrag bHi = *(const bfrag*)(Whi + bo);
        bfrag bLo = *(const bfrag*)(Wlo + bo);
        acc[c2][t] = __builtin_amdgcn_mfma_f32_16x16x32_bf16(aH[ks], bHi, acc[c2][t], 0, 0, 0);
        acc[c2][t] = __builtin_amdgcn_mfma_f32_16x16x32_bf16(aL[ks], bHi, acc[c2][t], 0, 0, 0);
        acc[c2][t] = __builtin_amdgcn_mfma_f32_16x16x32_bf16(aH[ks], bLo, acc[c2][t], 0, 0, 0);
      }
    }
  }

#pragma unroll
  for (int r = 0; r < 4; ++r) {
    int row = m_base + wv * 16 + quad * 4 + r;
    if (row < M) {
      float s = dinv[row];
#pragma unroll
      for (int c2 = 0; c2 < CHUNKS; ++c2)
#pragma unroll
        for (int t = 0; t < 4; ++t) {
          unsigned short h = bf16rne(acc[c2][t][r] * s);
          if (CSOUT)
            Y[((size_t)c2 * M + row) * 64 + t * 16 + col_l] = h;
          else
            Y[(size_t)row * OUTC + c2 * 64 + t * 16 + col_l] = h;
        }
    }
  }
}

__device__ inline void acc_add(float* a, uint4 d) {
  a[0] += bf16lo(d.x); a[1] += bf16hi(d.x);
  a[2] += bf16lo(d.y); a[3] += bf16hi(d.y);
  a[4] += bf16lo(d.z); a[5] += bf16hi(d.z);
  a[6] += bf16lo(d.w); a[7] += bf16hi(d.w);
}

// ---------------------------------------------------------------------------
// Aggregate v8 (C=128, cg=2 half-row split): block handles half cg = bid&1;
// under round-robin block->XCD dispatch each XCD's parity is fixed -> reads
// only xs2[cg] = contiguous [N][64ch] 12.8MB slice. 8 lanes/node gather one
// FULL 128B line per edge (v4's request profile). 8-edge chunks, 4 deep,
// ascending order. Output: standard [N][128] hi/lo planes.
// ---------------------------------------------------------------------------
__global__ __launch_bounds__(256) void aggregate_h2(const unsigned short* __restrict__ xs,
                                                    const int2* __restrict__ off2,
                                                    const int* __restrict__ cols,
                                                    const float* __restrict__ dinv,
                                                    const float* __restrict__ bias,
                                                    unsigned short* __restrict__ oh,
                                                    unsigned short* __restrict__ ol,
                                                    int N) {
  const int cg = blockIdx.x & 1;        // half-row group; fixed per XCD parity
  const int tile = blockIdx.x >> 1;
  const int t = threadIdx.x;
  const int gl = t & 7;                 // lane within node (8 x 16B = 128B)
  const int node = tile * 32 + (t >> 3);
  if (node >= N) return;

  const char* xb = (const char*)xs + (size_t)cg * N * 128;  // contiguous slice
  const unsigned go = (unsigned)gl * 16;

  float acc[8];
  {
    // self-loop row (pre-scaled by dinv[node] in the GEMM epilogue)
    uint4 d = *(const uint4*)(xb + (size_t)node * 128 + go);
    acc[0] = bf16lo(d.x); acc[1] = bf16hi(d.x);
    acc[2] = bf16lo(d.y); acc[3] = bf16hi(d.y);
    acc[4] = bf16lo(d.z); acc[5] = bf16hi(d.z);
    acc[6] = bf16lo(d.w); acc[7] = bf16hi(d.w);
  }

  const int2 oo = off2[node];
  const int en = oo.y;
  for (int e0 = oo.x; e0 < en; e0 += 8) {
    int col = __builtin_nontemporal_load(&cols[min(e0 + gl, en - 1)]);
    int m = en - e0;
    if (m > 8) m = 8;
    const int c1 = m - 1;
    for (int j = 0; j < m; j += 4) {
      int s0 = __shfl(col, min(j,     c1), 8);
      int s1 = __shfl(col, min(j + 1, c1), 8);
      int s2 = __shfl(col, min(j + 2, c1), 8);
      int s3 = __shfl(col, min(j + 3, c1), 8);
      uint4 d0 = *(const uint4*)(xb + (size_t)s0 * 128 + go);
      uint4 d1 = *(const uint4*)(xb + (size_t)s1 * 128 + go);
      uint4 d2 = *(const uint4*)(xb + (size_t)s2 * 128 + go);
      uint4 d3 = *(const uint4*)(xb + (size_t)s3 * 128 + go);
      acc_add(acc, d0);                       // j < m always
      if (j + 1 < m) acc_add(acc, d1);
      if (j + 2 < m) acc_add(acc, d2);
      if (j + 3 < m) acc_add(acc, d3);
    }
  }

  const float dd = dinv[node];
  const float4 bA = *(const float4*)(bias + cg * 64 + gl * 8);
  const float4 bB = *(const float4*)(bias + cg * 64 + gl * 8 + 4);
  float h[8];
  h[0] = acc[0] * dd + bA.x; h[1] = acc[1] * dd + bA.y;
  h[2] = acc[2] * dd + bA.z; h[3] = acc[3] * dd + bA.w;
  h[4] = acc[4] * dd + bB.x; h[5] = acc[5] * dd + bB.y;
  h[6] = acc[6] * dd + bB.z; h[7] = acc[7] * dd + bB.w;
#pragma unroll
  for (int q = 0; q < 8; ++q) h[q] = fmaxf(h[q], 0.f);

  u16x8 hv, lv;
#pragma unroll
  for (int q = 0; q < 8; ++q) {
    unsigned short hb = bf16rne(h[q]);
    hv[q] = hb;
    lv[q] = bf16rne(h[q] - __uint_as_float((unsigned)hb << 16));
  }
  const size_t ob = (size_t)node * 128 + cg * 64 + gl * 8;
  __builtin_nontemporal_store(hv, (u16x8*)(oh + ob));
  __builtin_nontemporal_store(lv, (u16x8*)(ol + ob));
}

// ---------------------------------------------------------------------------
// Aggregate v4 (kept for the C=64 final layer; standard [N][64] xs layout).
// ---------------------------------------------------------------------------
template <int C, bool RELU, bool SPLIT>
__global__ __launch_bounds__(256) void aggregate4(const unsigned short* __restrict__ xs,
                                                  const int2* __restrict__ off2,
                                                  const int* __restrict__ cols,
                                                  const float* __restrict__ dinv,
                                                  const float* __restrict__ bias,
                                                  float* __restrict__ outf,
                                                  unsigned short* __restrict__ oh,
                                                  unsigned short* __restrict__ ol,
                                                  int N) {
  constexpr int GL = C / 8;            // lanes per node
  constexpr int LSH = (GL == 16) ? 4 : 3;
  constexpr int NPBk = 256 / GL;       // nodes per block
  const int t = threadIdx.x;
  const int gl = t & (GL - 1);
  const int node = blockIdx.x * NPBk + (t >> LSH);
  if (node >= N) return;

  const unsigned co = (unsigned)gl * 16;  // byte offset of this lane's 8 ch
  const char* xb = (const char*)xs;

  float acc[8];
  {
    uint4 d = *(const uint4*)(xb + (size_t)node * (C * 2) + co);
    acc[0] = bf16lo(d.x); acc[1] = bf16hi(d.x);
    acc[2] = bf16lo(d.y); acc[3] = bf16hi(d.y);
    acc[4] = bf16lo(d.z); acc[5] = bf16hi(d.z);
    acc[6] = bf16lo(d.w); acc[7] = bf16hi(d.w);
  }

  const int2 oo = off2[node];
  const int en = oo.y;
  for (int e0 = oo.x; e0 < en; e0 += GL) {
    int col = __builtin_nontemporal_load(&cols[min(e0 + gl, en - 1)]);
    int m = en - e0;
    if (m > GL) m = GL;
    const int c1 = m - 1;
    for (int j = 0; j < m; j += 4) {
      int s0 = __shfl(col, min(j,     c1), GL);
      int s1 = __shfl(col, min(j + 1, c1), GL);
      int s2 = __shfl(col, min(j + 2, c1), GL);
      int s3 = __shfl(col, min(j + 3, c1), GL);
      uint4 d0 = *(const uint4*)(xb + (size_t)s0 * (C * 2) + co);
      uint4 d1 = *(const uint4*)(xb + (size_t)s1 * (C * 2) + co);
      uint4 d2 = *(const uint4*)(xb + (size_t)s2 * (C * 2) + co);
      uint4 d3 = *(const uint4*)(xb + (size_t)s3 * (C * 2) + co);
      acc_add(acc, d0);                       // j < m always
      if (j + 1 < m) acc_add(acc, d1);
      if (j + 2 < m) acc_add(acc, d2);
      if (j + 3 < m) acc_add(acc, d3);
    }
  }

  const float dd = dinv[node];
  const float4 bA = *(const float4*)(bias + gl * 8);
  const float4 bB = *(const float4*)(bias + gl * 8 + 4);
  float h[8];
  h[0] = acc[0] * dd + bA.x; h[1] = acc[1] * dd + bA.y;
  h[2] = acc[2] * dd + bA.z; h[3] = acc[3] * dd + bA.w;
  h[4] = acc[4] * dd + bB.x; h[5] = acc[5] * dd + bB.y;
  h[6] = acc[6] * dd + bB.z; h[7] = acc[7] * dd + bB.w;
  if (RELU) {
#pragma unroll
    for (int q = 0; q < 8; ++q) h[q] = fmaxf(h[q], 0.f);
  }
  if (SPLIT) {
    u16x8 hv, lv;
#pragma unroll
    for (int q = 0; q < 8; ++q) {
      unsigned short hb = bf16rne(h[q]);
      hv[q] = hb;
      lv[q] = bf16rne(h[q] - __uint_as_float((unsigned)hb << 16));
    }
    __builtin_nontemporal_store(hv, (u16x8*)(oh + (size_t)node * C + gl * 8));
    __builtin_nontemporal_store(lv, (u16x8*)(ol + (size_t)node * C + gl * 8));
  } else {
    f32x4 oA = {h[0], h[1], h[2], h[3]};
    f32x4 oB = {h[4], h[5], h[6], h[7]};
    __builtin_nontemporal_store(oA, (f32x4*)(outf + (size_t)node * C + gl * 8));
    __builtin_nontemporal_store(oB, (f32x4*)(outf + (size_t)node * C + gl * 8 + 4));
  }
}

// ---------------------------------------------------------------------------

extern "C" void kernel_launch(void* const* d_in, const int* in_sizes, int n_in,
                              void* d_out, int out_size, void* d_ws, size_t ws_size,
                              hipStream_t stream) {
  const float* x  = (const float*)d_in[0];
  const int*   ei = (const int*)d_in[1];
  const float* W1 = (const float*)d_in[2];
  const float* b1 = (const float*)d_in[3];
  const float* W2 = (const float*)d_in[4];
  const float* b2 = (const float*)d_in[5];
  const float* W3 = (const float*)d_in[6];
  const float* b3 = (const float*)d_in[7];

  const int N = in_sizes[0] / 128;
  const int E = in_sizes[1] / 2;
  const int* src = ei;
  const int* dst = ei + E;
  const int B = (N + NPB - 1) / NPB;

  char* w = (char*)d_ws;
  size_t p = 0;
  auto alloc = [&](size_t bytes) -> void* {
    void* r = w + p;
    p = (p + bytes + 255) & ~(size_t)255;
    return r;
  };
  float*    dinv   = (float*)alloc((size_t)N * 4);
  int2*     off2   = (int2*)alloc((size_t)N * 8);
  int*      cur    = (int*)alloc((size_t)B * 4);
  int*      binned = (int*)alloc((size_t)B * CAP * 4);
  int*      cols   = (int*)alloc((size_t)B * CAP * 4);
  unsigned short* xsb = (unsigned short*)alloc((size_t)N * 128 * 2);  // GEMM out
  unsigned short* hh  = (unsigned short*)alloc((size_t)N * 128 * 2);  // h hi plane
  unsigned short* hl  = (unsigned short*)alloc((size_t)N * 128 * 2);  // h lo plane
  unsigned short* w1h = (unsigned short*)alloc(128 * 128 * 2);
  unsigned short* w1l = (unsigned short*)alloc(128 * 128 * 2);
  unsigned short* w2h = (unsigned short*)alloc(128 * 128 * 2);
  unsigned short* w2l = (unsigned short*)alloc(128 * 128 * 2);
  unsigned short* w3h = (unsigned short*)alloc(64 * 128 * 2);
  unsigned short* w3l = (unsigned short*)alloc(64 * 128 * 2);

  split_w3<<<(40960 + B + 255) / 256, 256, 0, stream>>>(W1, W2, W3, w1h, w1l,
                                                        w2h, w2l, w3h, w3l,
                                                        cur, B);
  bin_edges<<<BIN_WGS, 256, 0, stream>>>(src, dst, cur, binned, E, B);
  build_buckets<<<B, 256, 0, stream>>>(binned, cur, cols, off2, dinv, N);

  const int gb = (N + 63) / 64;
  const int ah2 = ((N + 31) / 32) * 2;  // half-row split: 2 cgs per node tile
  const int ab64 = (N + 31) / 32;       // 32 nodes per block (C=64)

  gemm_xsplit<128, true><<<gb, 256, 0, stream>>>(x, w1h, w1l, dinv, xsb, N);
  aggregate_h2<<<ah2, 256, 0, stream>>>(xsb, off2, cols, dinv, b1, hh, hl, N);
  gemm_planes<128, true><<<gb, 256, 0, stream>>>(hh, hl, w2h, w2l, dinv, xsb, N);
  aggregate_h2<<<ah2, 256, 0, stream>>>(xsb, off2, cols, dinv, b2, hh, hl, N);
  gemm_planes<64, false><<<gb, 256, 0, stream>>>(hh, hl, w3h, w3l, dinv, xsb, N);
  aggregate4<64, false, false><<<ab64, 256, 0, stream>>>(xsb, off2, cols, dinv, b3,
                                                         (float*)d_out, nullptr,
                                                         nullptr, N);
}